// Round 11
// baseline (61.008 us; speedup 1.0000x reference)
//
#include <hip/hip_runtime.h>
#include <hip/hip_bf16.h>
#include <math.h>

#define B_   32
#define D_   128
#define L_   512
#define NH_  8
#define DK_  16
#define NB_  (NH_ * B_)          // 256 (n,b) pairs
#define PERNB 8192               // 512*16 fp16 elements per (n,b) plane

#define QKS  18    // Q/K LDS row stride ([*][16] + pad 2) — odd dword stride
#define VST  520   // V LDS row stride kernel2 ([16][512] + pad 8)
#define VSTS 136   // V LDS row stride kernel1 ([16][128] + pad 8)

#define LOG2E 1.4426950408889634f
#define QSC   (0.25f * LOG2E)          // fold 1/sqrt(dk)*log2(e) into Q
#define SH2   (-11.541560327111707f)   // -8*log2(e): softmax shift (MFMA acc)

typedef _Float16 h2 __attribute__((ext_vector_type(2)));
typedef _Float16 h4 __attribute__((ext_vector_type(4)));
typedef _Float16 h8 __attribute__((ext_vector_type(8)));
typedef __attribute__((ext_vector_type(4)))  float f32x4;
typedef __attribute__((ext_vector_type(16))) float f32x16;
typedef unsigned int u32x2 __attribute__((ext_vector_type(2)));
typedef unsigned int u32x4 __attribute__((ext_vector_type(4)));

__device__ __forceinline__ unsigned int cvt_pk_u(float a, float b) {
    return __builtin_bit_cast(unsigned int, __builtin_amdgcn_cvt_pkrtz(a, b));
}
__device__ __forceinline__ float zdot(unsigned int pk, float acc) {
    const h2 ones = {(_Float16)1.f, (_Float16)1.f};
    return __builtin_amdgcn_fdot2(__builtin_bit_cast(h2, pk), ones, acc, false);
}

#define MFMA_K32(a, b, c) __builtin_amdgcn_mfma_f32_16x16x32_f16((a), (b), (c), 0, 0, 0)
#define MFMA_32(a, b, c)  __builtin_amdgcn_mfma_f32_32x32x16_f16((a), (b), (c), 0, 0, 0)

// ---------------------------------------------------------------------------
// Kernel 0: xt[b][l][d] = (fp16) x[b][d][l]  — LDS-tiled transpose+cast.
// ---------------------------------------------------------------------------
__global__ __launch_bounds__(256) void xcast(
    const float* __restrict__ x,   // [B][D][L]
    _Float16* __restrict__ xt)     // [B][L][D]
{
    __shared__ _Float16 T[64][130];
    const int lt = blockIdx.x;
    const int b  = blockIdx.y;
    const int t  = threadIdx.x;
    const float* xb = x + (size_t)b * D_ * L_;
    _Float16* xtb = xt + (size_t)b * L_ * D_;

    #pragma unroll
    for (int i = t; i < 64 * 128; i += 256) {
        const int l = i & 63, d = i >> 6;
        T[l][d] = (_Float16)xb[(size_t)d * L_ + lt * 64 + l];
    }
    __syncthreads();
    #pragma unroll
    for (int i = t; i < 64 * 128; i += 256) {
        const int d = i & 127, l = i >> 7;
        xtb[(size_t)(lt * 64 + l) * D_ + d] = T[l][d];
    }
}

// ---------------------------------------------------------------------------
// Kernel 1: QKV projection for one (n,b) and one l-quarter (128 columns).
// grid (4, 256), 256 thr = 4 waves; wave wv owns l-span [32wv, 32wv+32).
// Outputs (fp16, coalesced via LDS transpose):
//   Qt[nb][l][k]  (pre-scaled by QSC)   Kt[nb][l][k]   Vt[nb][v][l]
// ---------------------------------------------------------------------------
__global__ __launch_bounds__(256) void qkv_mfma(
    const _Float16* __restrict__ xt,  // [B][L][D]
    const float* __restrict__ Wq,     // [NH][B][DK][D]
    const float* __restrict__ Wk,
    const float* __restrict__ Wv,
    _Float16* __restrict__ Qt,        // [NB][512][16]
    _Float16* __restrict__ Kt,        // [NB][512][16]
    _Float16* __restrict__ Vt)        // [NB][16][512]
{
    __shared__ __attribute__((aligned(16))) _Float16 QT[128 * QKS];
    __shared__ __attribute__((aligned(16))) _Float16 KT[128 * QKS];
    __shared__ __attribute__((aligned(16))) _Float16 VT[16 * VSTS];

    const int lq = blockIdx.x;        // l-quarter
    const int nb = blockIdx.y;
    const int n  = nb >> 5;
    const int b  = nb & 31;
    const int l0 = lq * 128;
    const int t  = threadIdx.x;
    const int wv = t >> 6;
    const int ln = t & 63;
    const int l16 = ln & 15;
    const int g4  = ln >> 4;

    const _Float16* xtb = xt + (size_t)b * L_ * D_;
    const size_t woff = (size_t)(n * B_ + b) * DK_ * D_;
    const float* pWq = Wq + woff;
    const float* pWk = Wk + woff;
    const float* pWv = Wv + woff;

    f32x4 Qa[2], Ka[2], Va[2];
    #pragma unroll
    for (int lt = 0; lt < 2; ++lt) {
        Qa[lt] = (f32x4){0.f,0.f,0.f,0.f};
        Ka[lt] = (f32x4){0.f,0.f,0.f,0.f};
        Va[lt] = (f32x4){0.f,0.f,0.f,0.f};
    }

    #pragma unroll
    for (int ks = 0; ks < 4; ++ks) {
        const int d0 = ks * 32 + g4 * 8;
        const float* aq = pWq + l16 * D_ + d0;
        const float* ak = pWk + l16 * D_ + d0;
        const float* av = pWv + l16 * D_ + d0;
        const float4 q0 = *(const float4*)aq, q1 = *(const float4*)(aq + 4);
        const float4 k0 = *(const float4*)ak, k1 = *(const float4*)(ak + 4);
        const float4 v0 = *(const float4*)av, v1 = *(const float4*)(av + 4);
        h8 Aq, Ak, Av;
        Aq[0]=(_Float16)q0.x; Aq[1]=(_Float16)q0.y; Aq[2]=(_Float16)q0.z; Aq[3]=(_Float16)q0.w;
        Aq[4]=(_Float16)q1.x; Aq[5]=(_Float16)q1.y; Aq[6]=(_Float16)q1.z; Aq[7]=(_Float16)q1.w;
        Ak[0]=(_Float16)k0.x; Ak[1]=(_Float16)k0.y; Ak[2]=(_Float16)k0.z; Ak[3]=(_Float16)k0.w;
        Ak[4]=(_Float16)k1.x; Ak[5]=(_Float16)k1.y; Ak[6]=(_Float16)k1.z; Ak[7]=(_Float16)k1.w;
        Av[0]=(_Float16)v0.x; Av[1]=(_Float16)v0.y; Av[2]=(_Float16)v0.z; Av[3]=(_Float16)v0.w;
        Av[4]=(_Float16)v1.x; Av[5]=(_Float16)v1.y; Av[6]=(_Float16)v1.z; Av[7]=(_Float16)v1.w;
        #pragma unroll
        for (int lt = 0; lt < 2; ++lt) {
            const int l = l0 + wv * 32 + lt * 16 + l16;
            const h8 Bx = *(const h8*)&xtb[(size_t)l * D_ + d0];
            Qa[lt] = MFMA_K32(Aq, Bx, Qa[lt]);
            Ka[lt] = MFMA_K32(Ak, Bx, Ka[lt]);
            Va[lt] = MFMA_K32(Av, Bx, Va[lt]);
        }
    }

    // D-frag (col l = l16, row k = 4g4+r) -> LDS
    #pragma unroll
    for (int lt = 0; lt < 2; ++lt) {
        const int ll = wv * 32 + lt * 16 + l16;     // 0..127
        h4 qv, kv;
        #pragma unroll
        for (int r = 0; r < 4; ++r) {
            qv[r] = (_Float16)(Qa[lt][r] * QSC);
            kv[r] = (_Float16)Ka[lt][r];
            VT[(g4 * 4 + r) * VSTS + ll] = (_Float16)Va[lt][r];
        }
        *(h4*)&QT[ll * QKS + g4 * 4] = qv;
        *(h4*)&KT[ll * QKS + g4 * 4] = kv;
    }
    __syncthreads();

    // coalesced copy out (16B per thread per plane)
    const size_t gb = (size_t)nb * PERNB;
    {
        const int row = t >> 1, half = t & 1;        // Q/K: 256 chunks
        const h8 q8 = *(const h8*)&QT[row * QKS + half * 8];
        const h8 k8 = *(const h8*)&KT[row * QKS + half * 8];
        *(h8*)&Qt[gb + (size_t)(l0 + row) * 16 + half * 8] = q8;
        *(h8*)&Kt[gb + (size_t)(l0 + row) * 16 + half * 8] = k8;
        const int vrow = t >> 4, cc = t & 15;        // V: 256 chunks
        const h8 v8 = *(const h8*)&VT[vrow * VSTS + cc * 8];
        *(h8*)&Vt[gb + (size_t)vrow * 512 + l0 + cc * 8] = v8;
    }
}

// ---------------------------------------------------------------------------
// Kernel 2: attention for one (n,b) and one m-quarter (128 scores columns).
// grid (4, 256) = 1024 blocks, 256 thr = 4 waves; LDS 35KB -> 4 blocks/CU
// with independent phase timing. Wave wv owns m-span [128mq+32wv, +32).
// ---------------------------------------------------------------------------
__global__ __launch_bounds__(256, 4) void attn2(
    const _Float16* __restrict__ Qt,  // [NB][512][16] (pre-scaled)
    const _Float16* __restrict__ Kt,  // [NB][512][16]
    const _Float16* __restrict__ Vt,  // [NB][16][512]
    _Float16* __restrict__ Ht)        // [B][512][128] transposed heads
{
    __shared__ __attribute__((aligned(16))) _Float16 Qh[512 * QKS];  // 18.4 KB
    __shared__ __attribute__((aligned(16))) _Float16 Vs[16 * VST];   // 16.6 KB

    const int mq = blockIdx.x;
    const int nb = blockIdx.y;
    const int n  = nb >> 5;
    const int b  = nb & 31;
    const int t  = threadIdx.x;
    const int wv = t >> 6;
    const int ln = t & 63;
    const int l16 = ln & 15;
    const int lm  = ln & 31;
    const int hi  = ln >> 5;

    const size_t gb = (size_t)nb * PERNB;
    const int m0 = mq * 128 + wv * 32;

    // K direct to regs (global, coalesced across the wave)
    const h8 Bk = *(const h8*)&Kt[gb + (size_t)(m0 + lm) * 16 + 8 * hi];

    // stage Q (all 512 l) and V into LDS
    #pragma unroll
    for (int i = 0; i < 4; ++i) {
        const int c = t + i * 256;                 // 0..1023 16B chunks
        const int row = c >> 1, half = c & 1;
        const h8 q8 = *(const h8*)&Qt[gb + (size_t)c * 8];
        *(h8*)&Qh[row * QKS + half * 8] = q8;
        const int vrow = c >> 6, cc = c & 63;
        const h8 v8 = *(const h8*)&Vt[gb + (size_t)c * 8];
        *(h8*)&Vs[vrow * VST + cc * 8] = v8;
    }
    __syncthreads();

    f32x16 shiftacc, pvacc;
    #pragma unroll
    for (int i = 0; i < 16; ++i) { shiftacc[i] = SH2; pvacc[i] = 0.f; }
    float Za = 0.f;

    for (int t32 = 0; t32 < 16; ++t32) {
        const int lb = t32 * 32;
        const h8 Aq = *(const h8*)&Qh[(lb + lm) * QKS + 8 * hi];
        const f32x16 sc = MFMA_32(Aq, Bk, shiftacc);   // pre-shifted scores

        float p[16];
        #pragma unroll
        for (int r = 0; r < 16; ++r) p[r] = exp2f(sc[r]);

        const unsigned int a0 = cvt_pk_u(p[0],  p[1]);
        const unsigned int a1 = cvt_pk_u(p[2],  p[3]);
        const unsigned int a2 = cvt_pk_u(p[4],  p[5]);
        const unsigned int a3 = cvt_pk_u(p[6],  p[7]);
        const unsigned int a4 = cvt_pk_u(p[8],  p[9]);
        const unsigned int a5 = cvt_pk_u(p[10], p[11]);
        const unsigned int a6 = cvt_pk_u(p[12], p[13]);
        const unsigned int a7 = cvt_pk_u(p[14], p[15]);

        Za = zdot(a0, Za); Za = zdot(a1, Za); Za = zdot(a2, Za); Za = zdot(a3, Za);
        Za = zdot(a4, Za); Za = zdot(a5, Za); Za = zdot(a6, Za); Za = zdot(a7, Za);

        const u32x2 s02 = __builtin_amdgcn_permlane32_swap(a0, a2, false, false);
        const u32x2 s13 = __builtin_amdgcn_permlane32_swap(a1, a3, false, false);
        const u32x2 s46 = __builtin_amdgcn_permlane32_swap(a4, a6, false, false);
        const u32x2 s57 = __builtin_amdgcn_permlane32_swap(a5, a7, false, false);
        const h8 A1 = __builtin_bit_cast(h8, (u32x4){s02.x, s13.x, s02.y, s13.y});
        const h8 A2 = __builtin_bit_cast(h8, (u32x4){s46.x, s57.x, s46.y, s57.y});

        const h8 Bv1 = *(const h8*)&Vs[l16 * VST + lb + 8 * hi];
        const h8 Bv2 = *(const h8*)&Vs[l16 * VST + lb + 16 + 8 * hi];
        pvacc = MFMA_32(A1, Bv1, pvacc);
        pvacc = MFMA_32(A2, Bv2, pvacc);
    }

    // epilogue: Z[m] at lane m (+32 dup); redistribute to D-frag rows.
    Za += __shfl_xor(Za, 32);
    const float rz = 1.f / Za;              // Z for m = m0 + lm
    const int kk = (NH_ - 1 - n) * 16 + l16;
    _Float16* Hb = Ht + (size_t)b * 512 * 128;
    #pragma unroll
    for (int r = 0; r < 16; ++r) {
        const int mrow = (r & 3) + 8 * (r >> 2) + 4 * hi;
        const float rzr = __shfl(rz, mrow);
        if (lm < 16) {
            Hb[(size_t)(m0 + mrow) * 128 + kk] =
                (_Float16)(pvacc[r] * rzr);
        }
    }
}

// ---------------------------------------------------------------------------
// Kernel B: out[b] = Wo[b] (128x128) @ heads[b] (128x512), fp16 MFMA,
// pure-register. grid (8 col-tiles, 32 b), 512 thr; wave = 16-row m-tile.
// ---------------------------------------------------------------------------
__global__ __launch_bounds__(512) void out_proj_mfma(
    const float* __restrict__ Wo,        // [B][128][128]
    const _Float16* __restrict__ Ht,     // [B][512][128]
    float* __restrict__ out)             // [B][128][512]
{
    const int ct = blockIdx.x;
    const int b  = blockIdx.y;
    const int t  = threadIdx.x;
    const int wv = t >> 6;
    const int ln = t & 63;
    const int l16 = ln & 15;
    const int g4  = ln >> 4;

    const float* Wb = Wo + (size_t)b * D_ * D_;
    const _Float16* Hb = Ht + (size_t)b * 512 * 128;

    f32x4 acc[4];
    #pragma unroll
    for (int nt = 0; nt < 4; ++nt) acc[nt] = (f32x4){0.f,0.f,0.f,0.f};

    #pragma unroll
    for (int ks = 0; ks < 4; ++ks) {
        const int k0 = ks * 32 + g4 * 8;
        const float* ap = Wb + (size_t)(wv * 16 + l16) * D_ + k0;
        h8 Ah;
        #pragma unroll
        for (int j = 0; j < 8; ++j) Ah[j] = (_Float16)ap[j];
        #pragma unroll
        for (int nt = 0; nt < 4; ++nt) {
            const h8 Bh = *(const h8*)&Hb[(size_t)(ct * 64 + nt * 16 + l16) * 128 + k0];
            acc[nt] = MFMA_K32(Ah, Bh, acc[nt]);
        }
    }

    float* ob = out + (size_t)b * D_ * L_;
    #pragma unroll
    for (int nt = 0; nt < 4; ++nt) {
        #pragma unroll
        for (int r = 0; r < 4; ++r) {
            ob[(size_t)(wv * 16 + g4 * 4 + r) * L_ + ct * 64 + nt * 16 + l16] = acc[nt][r];
        }
    }
}

extern "C" void kernel_launch(void* const* d_in, const int* in_sizes, int n_in,
                              void* d_out, int out_size, void* d_ws, size_t ws_size,
                              hipStream_t stream)
{
    const float* x  = (const float*)d_in[0];
    const float* Wq = (const float*)d_in[1];
    const float* Wk = (const float*)d_in[2];
    const float* Wv = (const float*)d_in[3];
    const float* Wo = (const float*)d_in[4];
    float* out = (float*)d_out;

    _Float16* Ht = (_Float16*)d_ws;                       // 4 MB
    _Float16* xt = Ht + (size_t)B_ * 512 * 128;           // 4 MB
    _Float16* Qt = xt + (size_t)B_ * 512 * 128;           // 4 MB
    _Float16* Kt = Qt + (size_t)NB_ * PERNB;              // 4 MB
    _Float16* Vt = Kt + (size_t)NB_ * PERNB;              // 4 MB

    xcast<<<dim3(8, B_), dim3(256), 0, stream>>>(x, xt);
    qkv_mfma<<<dim3(4, NB_), dim3(256), 0, stream>>>(xt, Wq, Wk, Wv, Qt, Kt, Vt);
    attn2<<<dim3(4, NB_), dim3(256), 0, stream>>>(Qt, Kt, Vt, Ht);
    out_proj_mfma<<<dim3(8, B_), dim3(512), 0, stream>>>(Wo, Ht, out);
}

// Round 12
// 43.952 us; speedup vs baseline: 1.3881x; 1.3881x over previous
//
#include <hip/hip_runtime.h>
#include <hip/hip_bf16.h>
#include <math.h>

#define B_   32
#define D_   128
#define L_   512
#define NH_  8
#define DK_  16

#define QKS  18    // Qh/Kh row stride in f16 elems ([512][16] + pad 2)
#define VST  520   // V row stride ([32][512] + pad 8); rows 16-31 = 1.0 (free-Z)

#define LOG2E 1.4426950408889634f
#define QSC   (0.25f * LOG2E)          // fold 1/sqrt(dk) * log2(e) into Q
#define SH2   (-11.541560327111707f)   // -8 * log2(e): softmax shift, in MFMA acc

typedef _Float16 h2 __attribute__((ext_vector_type(2)));
typedef _Float16 h4 __attribute__((ext_vector_type(4)));
typedef _Float16 h8 __attribute__((ext_vector_type(8)));
typedef __attribute__((ext_vector_type(4)))  float f32x4;
typedef __attribute__((ext_vector_type(16))) float f32x16;
typedef unsigned int u32x2 __attribute__((ext_vector_type(2)));
typedef unsigned int u32x4 __attribute__((ext_vector_type(4)));

__device__ __forceinline__ unsigned int cvt_pk_u(float a, float b) {
    return __builtin_bit_cast(unsigned int, __builtin_amdgcn_cvt_pkrtz(a, b));
}

#define MFMA_K32(a, b, c) __builtin_amdgcn_mfma_f32_16x16x32_f16((a), (b), (c), 0, 0, 0)
#define MFMA_32(a, b, c)  __builtin_amdgcn_mfma_f32_32x32x16_f16((a), (b), (c), 0, 0, 0)

// ---------------------------------------------------------------------------
// Kernel 0: xt[b][l][d] = (fp16) x[b][d][l]  — LDS-tiled transpose+cast.
// ---------------------------------------------------------------------------
__global__ __launch_bounds__(256) void xcast(
    const float* __restrict__ x,   // [B][D][L]
    _Float16* __restrict__ xt)     // [B][L][D]
{
    __shared__ _Float16 T[64][130];
    const int lt = blockIdx.x;
    const int b  = blockIdx.y;
    const int t  = threadIdx.x;
    const float* xb = x + (size_t)b * D_ * L_;
    _Float16* xtb = xt + (size_t)b * L_ * D_;

    #pragma unroll
    for (int i = t; i < 64 * 128; i += 256) {
        const int l = i & 63, d = i >> 6;
        T[l][d] = (_Float16)xb[(size_t)d * L_ + lt * 64 + l];
    }
    __syncthreads();
    #pragma unroll
    for (int i = t; i < 64 * 128; i += 256) {
        const int d = i & 127, l = i >> 7;
        xtb[(size_t)(lt * 64 + l) * D_ + d] = T[l][d];
    }
}

// ---------------------------------------------------------------------------
// Kernel A: fused attention. P1: 16x16x32 fp16 MFMA. P2: 32x32x16 tiles,
// ILP-2 over l-tile pairs, softmax shift folded into the MFMA accumulator,
// raw v_exp_f32 (trans pipe, not libm expansion), P->PV A-frag via
// permlane32_swap, Z FREE from PV MFMA cols 16-31 (V rows 16-31 = 1.0).
// grid 256 = (n,b), 1024 thr = 16 waves; wave wv owns m-span [32wv, +32).
// ---------------------------------------------------------------------------
__global__ __launch_bounds__(1024, 4) void attn_mfma(
    const _Float16* __restrict__ xt,  // [B][L][D] fp16
    const float* __restrict__ Wq,     // [NH][B][DK][D]
    const float* __restrict__ Wk,
    const float* __restrict__ Wv,
    _Float16* __restrict__ Ht)        // [B][512][128] fp16 (transposed heads)
{
    __shared__ __attribute__((aligned(16))) _Float16 Qh[512 * QKS];  // 18.4 KB
    __shared__ __attribute__((aligned(16))) _Float16 Kh[512 * QKS];  // 18.4 KB
    __shared__ __attribute__((aligned(16))) _Float16 Vs[32 * VST];   // 33.3 KB

    const int nb = blockIdx.x;
    const int n  = nb >> 5;
    const int b  = nb & 31;
    const int t  = threadIdx.x;
    const int wv = t >> 6;          // wave 0..15
    const int ln = t & 63;
    const int l16 = ln & 15;
    const int g4  = ln >> 4;        // 0..3
    const int lm  = ln & 31;        // 32-tile row/col index
    const int hi  = ln >> 5;        // 0..1

    const _Float16* xtb = xt + (size_t)b * L_ * D_;
    const size_t woff = (size_t)(n * B_ + b) * DK_ * D_;
    const float* pWq = Wq + woff;
    const float* pWk = Wk + woff;
    const float* pWv = Wv + woff;

    // V rows 16..31 = 1.0 -> PV accumulator cols 16..31 become Z[m].
    {
        const h8 ones8 = {(_Float16)1.f,(_Float16)1.f,(_Float16)1.f,(_Float16)1.f,
                          (_Float16)1.f,(_Float16)1.f,(_Float16)1.f,(_Float16)1.f};
        const int row = 16 + (t >> 6), cc = (t & 63) * 8;
        *(h8*)&Vs[row * VST + cc] = ones8;
    }

    // ================= P1: Q,K,V = W @ x  (fp16 16x16x32 MFMA) ============
    f32x4 Qa[2], Ka[2], Va[2];
    #pragma unroll
    for (int lt = 0; lt < 2; ++lt) {
        Qa[lt] = (f32x4){0.f,0.f,0.f,0.f};
        Ka[lt] = (f32x4){0.f,0.f,0.f,0.f};
        Va[lt] = (f32x4){0.f,0.f,0.f,0.f};
    }

    #pragma unroll
    for (int ks = 0; ks < 4; ++ks) {
        const int d0 = ks * 32 + g4 * 8;       // A/B-frag k = 8*g4 + j
        const float* aq = pWq + l16 * D_ + d0;
        const float* ak = pWk + l16 * D_ + d0;
        const float* av = pWv + l16 * D_ + d0;
        const float4 q0 = *(const float4*)aq, q1 = *(const float4*)(aq + 4);
        const float4 k0 = *(const float4*)ak, k1 = *(const float4*)(ak + 4);
        const float4 v0 = *(const float4*)av, v1 = *(const float4*)(av + 4);
        h8 Aq, Ak, Av;
        Aq[0]=(_Float16)q0.x; Aq[1]=(_Float16)q0.y; Aq[2]=(_Float16)q0.z; Aq[3]=(_Float16)q0.w;
        Aq[4]=(_Float16)q1.x; Aq[5]=(_Float16)q1.y; Aq[6]=(_Float16)q1.z; Aq[7]=(_Float16)q1.w;
        Ak[0]=(_Float16)k0.x; Ak[1]=(_Float16)k0.y; Ak[2]=(_Float16)k0.z; Ak[3]=(_Float16)k0.w;
        Ak[4]=(_Float16)k1.x; Ak[5]=(_Float16)k1.y; Ak[6]=(_Float16)k1.z; Ak[7]=(_Float16)k1.w;
        Av[0]=(_Float16)v0.x; Av[1]=(_Float16)v0.y; Av[2]=(_Float16)v0.z; Av[3]=(_Float16)v0.w;
        Av[4]=(_Float16)v1.x; Av[5]=(_Float16)v1.y; Av[6]=(_Float16)v1.z; Av[7]=(_Float16)v1.w;
        #pragma unroll
        for (int lt = 0; lt < 2; ++lt) {
            const int l = wv * 32 + lt * 16 + l16;
            const h8 Bx = *(const h8*)&xtb[(size_t)l * D_ + d0];
            Qa[lt] = MFMA_K32(Aq, Bx, Qa[lt]);
            Ka[lt] = MFMA_K32(Ak, Bx, Ka[lt]);
            Va[lt] = MFMA_K32(Av, Bx, Va[lt]);
        }
    }

    // Q^T (pre-scaled by 0.25*log2e), K^T, V -> LDS.
    #pragma unroll
    for (int lt = 0; lt < 2; ++lt) {
        const int l = wv * 32 + lt * 16 + l16;
        h4 qv, kv;
        #pragma unroll
        for (int r = 0; r < 4; ++r) {
            qv[r] = (_Float16)(Qa[lt][r] * QSC);
            kv[r] = (_Float16)Ka[lt][r];
            Vs[(g4 * 4 + r) * VST + l] = (_Float16)Va[lt][r];
        }
        *(h4*)&Qh[l * QKS + g4 * 4] = qv;
        *(h4*)&Kh[l * QKS + g4 * 4] = kv;
    }
    __syncthreads();

    // ================= P2: 32x32 tiles, ILP-2 over l-pairs ================
    const int m0 = wv * 32;
    const h8 Bk = *(const h8*)&Kh[(m0 + lm) * QKS + 8 * hi];

    f32x16 shiftacc, pvacc;
    #pragma unroll
    for (int i = 0; i < 16; ++i) { shiftacc[i] = SH2; pvacc[i] = 0.f; }

    for (int tp = 0; tp < 8; ++tp) {
        const int lbA = tp * 64;
        const int lbB = lbA + 32;
        // two independent chains (A: l-tile 2tp, B: l-tile 2tp+1)
        const h8 AqA = *(const h8*)&Qh[(lbA + lm) * QKS + 8 * hi];
        const h8 AqB = *(const h8*)&Qh[(lbB + lm) * QKS + 8 * hi];
        const f32x16 scA = MFMA_32(AqA, Bk, shiftacc);  // pre-shifted scores
        const f32x16 scB = MFMA_32(AqB, Bk, shiftacc);

        float pA[16], pB[16];
        #pragma unroll
        for (int r = 0; r < 16; ++r) pA[r] = __builtin_amdgcn_exp2f(scA[r]);
        #pragma unroll
        for (int r = 0; r < 16; ++r) pB[r] = __builtin_amdgcn_exp2f(scB[r]);

        const unsigned int a0 = cvt_pk_u(pA[0],  pA[1]);
        const unsigned int a1 = cvt_pk_u(pA[2],  pA[3]);
        const unsigned int a2 = cvt_pk_u(pA[4],  pA[5]);
        const unsigned int a3 = cvt_pk_u(pA[6],  pA[7]);
        const unsigned int a4 = cvt_pk_u(pA[8],  pA[9]);
        const unsigned int a5 = cvt_pk_u(pA[10], pA[11]);
        const unsigned int a6 = cvt_pk_u(pA[12], pA[13]);
        const unsigned int a7 = cvt_pk_u(pA[14], pA[15]);
        const unsigned int b0 = cvt_pk_u(pB[0],  pB[1]);
        const unsigned int b1 = cvt_pk_u(pB[2],  pB[3]);
        const unsigned int b2 = cvt_pk_u(pB[4],  pB[5]);
        const unsigned int b3 = cvt_pk_u(pB[6],  pB[7]);
        const unsigned int b4 = cvt_pk_u(pB[8],  pB[9]);
        const unsigned int b5 = cvt_pk_u(pB[10], pB[11]);
        const unsigned int b6 = cvt_pk_u(pB[12], pB[13]);
        const unsigned int b7 = cvt_pk_u(pB[14], pB[15]);

        const u32x2 sA02 = __builtin_amdgcn_permlane32_swap(a0, a2, false, false);
        const u32x2 sA13 = __builtin_amdgcn_permlane32_swap(a1, a3, false, false);
        const u32x2 sA46 = __builtin_amdgcn_permlane32_swap(a4, a6, false, false);
        const u32x2 sA57 = __builtin_amdgcn_permlane32_swap(a5, a7, false, false);
        const u32x2 sB02 = __builtin_amdgcn_permlane32_swap(b0, b2, false, false);
        const u32x2 sB13 = __builtin_amdgcn_permlane32_swap(b1, b3, false, false);
        const u32x2 sB46 = __builtin_amdgcn_permlane32_swap(b4, b6, false, false);
        const u32x2 sB57 = __builtin_amdgcn_permlane32_swap(b5, b7, false, false);
        const h8 A1 = __builtin_bit_cast(h8, (u32x4){sA02.x, sA13.x, sA02.y, sA13.y});
        const h8 A2 = __builtin_bit_cast(h8, (u32x4){sA46.x, sA57.x, sA46.y, sA57.y});
        const h8 B1 = __builtin_bit_cast(h8, (u32x4){sB02.x, sB13.x, sB02.y, sB13.y});
        const h8 B2 = __builtin_bit_cast(h8, (u32x4){sB46.x, sB57.x, sB46.y, sB57.y});

        // B-frag row = lm: rows 0-15 = V, rows 16-31 = ones (Z columns)
        const h8 BvA1 = *(const h8*)&Vs[lm * VST + lbA + 8 * hi];
        const h8 BvA2 = *(const h8*)&Vs[lm * VST + lbA + 16 + 8 * hi];
        const h8 BvB1 = *(const h8*)&Vs[lm * VST + lbB + 8 * hi];
        const h8 BvB2 = *(const h8*)&Vs[lm * VST + lbB + 16 + 8 * hi];
        pvacc = MFMA_32(A1, BvA1, pvacc);
        pvacc = MFMA_32(A2, BvA2, pvacc);
        pvacc = MFMA_32(B1, BvB1, pvacc);
        pvacc = MFMA_32(B2, BvB2, pvacc);
    }

    // epilogue: Z[mrow] sits in cols 16-31 (lanes 16-31 / 48-63), reg r.
    const int kk = (NH_ - 1 - n) * 16 + l16;
    const int zlane = 16 + 32 * hi;
    _Float16* Hb = Ht + (size_t)b * 512 * 128;
    #pragma unroll
    for (int r = 0; r < 16; ++r) {
        const int mrow = (r & 3) + 8 * (r >> 2) + 4 * hi;
        const float zr  = __shfl(pvacc[r], zlane);
        const float rzr = __builtin_amdgcn_rcpf(zr);
        if (lm < 16) {
            Hb[(size_t)(m0 + mrow) * 128 + kk] =
                (_Float16)(pvacc[r] * rzr);
        }
    }
}

// ---------------------------------------------------------------------------
// Kernel B: out[b] = Wo[b] (128x128) @ heads[b] (128x512), fp16 MFMA,
// pure-register. grid (8 col-tiles, 32 b), 512 thr; wave = 16-row m-tile.
// ---------------------------------------------------------------------------
__global__ __launch_bounds__(512) void out_proj_mfma(
    const float* __restrict__ Wo,        // [B][128][128]
    const _Float16* __restrict__ Ht,     // [B][512][128]
    float* __restrict__ out)             // [B][128][512]
{
    const int ct = blockIdx.x;     // col0 = ct*64
    const int b  = blockIdx.y;
    const int t  = threadIdx.x;
    const int wv = t >> 6;
    const int ln = t & 63;
    const int l16 = ln & 15;
    const int g4  = ln >> 4;

    const float* Wb = Wo + (size_t)b * D_ * D_;
    const _Float16* Hb = Ht + (size_t)b * 512 * 128;

    f32x4 acc[4];
    #pragma unroll
    for (int nt = 0; nt < 4; ++nt) acc[nt] = (f32x4){0.f,0.f,0.f,0.f};

    #pragma unroll
    for (int ks = 0; ks < 4; ++ks) {
        const int k0 = ks * 32 + g4 * 8;
        const float* ap = Wb + (size_t)(wv * 16 + l16) * D_ + k0;
        h8 Ah;
        #pragma unroll
        for (int j = 0; j < 8; ++j) Ah[j] = (_Float16)ap[j];
        #pragma unroll
        for (int nt = 0; nt < 4; ++nt) {
            const h8 Bh = *(const h8*)&Hb[(size_t)(ct * 64 + nt * 16 + l16) * 128 + k0];
            acc[nt] = MFMA_K32(Ah, Bh, acc[nt]);
        }
    }

    float* ob = out + (size_t)b * D_ * L_;
    #pragma unroll
    for (int nt = 0; nt < 4; ++nt) {
        #pragma unroll
        for (int r = 0; r < 4; ++r) {
            ob[(size_t)(wv * 16 + g4 * 4 + r) * L_ + ct * 64 + nt * 16 + l16] = acc[nt][r];
        }
    }
}

extern "C" void kernel_launch(void* const* d_in, const int* in_sizes, int n_in,
                              void* d_out, int out_size, void* d_ws, size_t ws_size,
                              hipStream_t stream)
{
    const float* x  = (const float*)d_in[0];
    const float* Wq = (const float*)d_in[1];
    const float* Wk = (const float*)d_in[2];
    const float* Wv = (const float*)d_in[3];
    const float* Wo = (const float*)d_in[4];
    float* out = (float*)d_out;

    _Float16* Ht = (_Float16*)d_ws;                       // 4 MB
    _Float16* xt = Ht + (size_t)B_ * 512 * 128;           // 4 MB

    xcast<<<dim3(8, B_), dim3(256), 0, stream>>>(x, xt);
    attn_mfma<<<dim3(NH_ * B_), dim3(1024), 0, stream>>>(xt, Wq, Wk, Wv, Ht);
    out_proj_mfma<<<dim3(8, B_), dim3(512), 0, stream>>>(Wo, Ht, out);
}

// Round 13
// 40.789 us; speedup vs baseline: 1.4957x; 1.0775x over previous
//
#include <hip/hip_runtime.h>
#include <hip/hip_bf16.h>
#include <math.h>

#define B_   32
#define D_   128
#define L_   512
#define NH_  8
#define DK_  16

#define QKS  18    // Qh/Kh row stride in f16 elems ([512][16] + pad 2)
#define VST  520   // V row stride ([16][512] + pad 8)

#define LOG2E 1.4426950408889634f
#define QSC   (0.25f * LOG2E)          // fold 1/sqrt(dk) * log2(e) into Q
#define SH2   (-11.541560327111707f)   // -8 * log2(e): softmax shift, in MFMA acc

typedef _Float16 h2 __attribute__((ext_vector_type(2)));
typedef _Float16 h4 __attribute__((ext_vector_type(4)));
typedef _Float16 h8 __attribute__((ext_vector_type(8)));
typedef __attribute__((ext_vector_type(4)))  float f32x4;
typedef __attribute__((ext_vector_type(16))) float f32x16;
typedef unsigned int u32x2 __attribute__((ext_vector_type(2)));
typedef unsigned int u32x4 __attribute__((ext_vector_type(4)));

__device__ __forceinline__ unsigned int cvt_pk_u(float a, float b) {
    return __builtin_bit_cast(unsigned int, __builtin_amdgcn_cvt_pkrtz(a, b));
}

#define MFMA_K32(a, b, c) __builtin_amdgcn_mfma_f32_16x16x32_f16((a), (b), (c), 0, 0, 0)
#define MFMA_32(a, b, c)  __builtin_amdgcn_mfma_f32_32x32x16_f16((a), (b), (c), 0, 0, 0)

// ---------------------------------------------------------------------------
// Kernel 0: xt[b][l][d] = (fp16) x[b][d][l]  — LDS-tiled transpose+cast.
// ---------------------------------------------------------------------------
__global__ __launch_bounds__(256) void xcast(
    const float* __restrict__ x,   // [B][D][L]
    _Float16* __restrict__ xt)     // [B][L][D]
{
    __shared__ _Float16 T[64][130];
    const int lt = blockIdx.x;
    const int b  = blockIdx.y;
    const int t  = threadIdx.x;
    const float* xb = x + (size_t)b * D_ * L_;
    _Float16* xtb = xt + (size_t)b * L_ * D_;

    #pragma unroll
    for (int i = t; i < 64 * 128; i += 256) {
        const int l = i & 63, d = i >> 6;
        T[l][d] = (_Float16)xb[(size_t)d * L_ + lt * 64 + l];
    }
    __syncthreads();
    #pragma unroll
    for (int i = t; i < 64 * 128; i += 256) {
        const int d = i & 127, l = i >> 7;
        xtb[(size_t)(lt * 64 + l) * D_ + d] = T[l][d];
    }
}

// ---------------------------------------------------------------------------
// Kernel A: fused attention. 512 thr = 8 waves, LDS 53.5KB -> 2 independent
// blocks/CU (phase decorrelation: one block's P1 overlaps the other's P2).
// P1: wave owns 64 l (4 l-tiles), 16x16x32 fp16 MFMA.
// P2: wave owns 64 m (2 x 32-m-tiles = 2 independent chains), 32x32x16;
// shift-in-accumulator, raw v_exp_f32, permlane32_swap P->A-frag, free Z
// via constant-1.0 B-frag halves (no ones rows in LDS).
// ---------------------------------------------------------------------------
__global__ __launch_bounds__(512, 4) void attn_mfma(
    const _Float16* __restrict__ xt,  // [B][L][D] fp16
    const float* __restrict__ Wq,     // [NH][B][DK][D]
    const float* __restrict__ Wk,
    const float* __restrict__ Wv,
    _Float16* __restrict__ Ht)        // [B][512][128] fp16 (transposed heads)
{
    __shared__ __attribute__((aligned(16))) _Float16 Qh[512 * QKS];  // 18.4 KB
    __shared__ __attribute__((aligned(16))) _Float16 Kh[512 * QKS];  // 18.4 KB
    __shared__ __attribute__((aligned(16))) _Float16 Vs[16 * VST];   // 16.6 KB

    const int nb = blockIdx.x;
    const int n  = nb >> 5;
    const int b  = nb & 31;
    const int t  = threadIdx.x;
    const int wv = t >> 6;          // wave 0..7
    const int ln = t & 63;
    const int l16 = ln & 15;
    const int g4  = ln >> 4;        // 0..3
    const int lm  = ln & 31;        // 32-tile row/col index
    const int hi  = ln >> 5;        // 0..1

    const _Float16* xtb = xt + (size_t)b * L_ * D_;
    const size_t woff = (size_t)(n * B_ + b) * DK_ * D_;
    const float* pWq = Wq + woff;
    const float* pWk = Wk + woff;
    const float* pWv = Wv + woff;

    // ================= P1: Q,K,V = W @ x  (fp16 16x16x32 MFMA) ============
    f32x4 Qa[4], Ka[4], Va[4];
    #pragma unroll
    for (int lt = 0; lt < 4; ++lt) {
        Qa[lt] = (f32x4){0.f,0.f,0.f,0.f};
        Ka[lt] = (f32x4){0.f,0.f,0.f,0.f};
        Va[lt] = (f32x4){0.f,0.f,0.f,0.f};
    }

    #pragma unroll
    for (int ks = 0; ks < 4; ++ks) {
        const int d0 = ks * 32 + g4 * 8;       // A/B-frag k = 8*g4 + j
        const float* aq = pWq + l16 * D_ + d0;
        const float* ak = pWk + l16 * D_ + d0;
        const float* av = pWv + l16 * D_ + d0;
        const float4 q0 = *(const float4*)aq, q1 = *(const float4*)(aq + 4);
        const float4 k0 = *(const float4*)ak, k1 = *(const float4*)(ak + 4);
        const float4 v0 = *(const float4*)av, v1 = *(const float4*)(av + 4);
        h8 Aq, Ak, Av;
        Aq[0]=(_Float16)q0.x; Aq[1]=(_Float16)q0.y; Aq[2]=(_Float16)q0.z; Aq[3]=(_Float16)q0.w;
        Aq[4]=(_Float16)q1.x; Aq[5]=(_Float16)q1.y; Aq[6]=(_Float16)q1.z; Aq[7]=(_Float16)q1.w;
        Ak[0]=(_Float16)k0.x; Ak[1]=(_Float16)k0.y; Ak[2]=(_Float16)k0.z; Ak[3]=(_Float16)k0.w;
        Ak[4]=(_Float16)k1.x; Ak[5]=(_Float16)k1.y; Ak[6]=(_Float16)k1.z; Ak[7]=(_Float16)k1.w;
        Av[0]=(_Float16)v0.x; Av[1]=(_Float16)v0.y; Av[2]=(_Float16)v0.z; Av[3]=(_Float16)v0.w;
        Av[4]=(_Float16)v1.x; Av[5]=(_Float16)v1.y; Av[6]=(_Float16)v1.z; Av[7]=(_Float16)v1.w;
        #pragma unroll
        for (int lt = 0; lt < 4; ++lt) {
            const int l = wv * 64 + lt * 16 + l16;
            const h8 Bx = *(const h8*)&xtb[(size_t)l * D_ + d0];
            Qa[lt] = MFMA_K32(Aq, Bx, Qa[lt]);
            Ka[lt] = MFMA_K32(Ak, Bx, Ka[lt]);
            Va[lt] = MFMA_K32(Av, Bx, Va[lt]);
        }
    }

    // Q^T (pre-scaled by 0.25*log2e), K^T, V -> LDS.
    #pragma unroll
    for (int lt = 0; lt < 4; ++lt) {
        const int l = wv * 64 + lt * 16 + l16;
        h4 qv, kv;
        #pragma unroll
        for (int r = 0; r < 4; ++r) {
            qv[r] = (_Float16)(Qa[lt][r] * QSC);
            kv[r] = (_Float16)Ka[lt][r];
            Vs[(g4 * 4 + r) * VST + l] = (_Float16)Va[lt][r];
        }
        *(h4*)&Qh[l * QKS + g4 * 4] = qv;
        *(h4*)&Kh[l * QKS + g4 * 4] = kv;
    }
    __syncthreads();

    // ====== P2: 2 x 32-m-tiles per wave, independent chains, free Z =======
    const int m0 = wv * 64;
    const h8 Bk0 = *(const h8*)&Kh[(m0 + lm) * QKS + 8 * hi];
    const h8 Bk1 = *(const h8*)&Kh[(m0 + 32 + lm) * QKS + 8 * hi];

    f32x16 shiftacc, pv0, pv1;
    #pragma unroll
    for (int i = 0; i < 16; ++i) { shiftacc[i] = SH2; pv0[i] = 0.f; pv1[i] = 0.f; }

    const bool vsel = (lm < 16);
    const int  vrow = lm & 15;
    const h8 ones8 = {(_Float16)1.f,(_Float16)1.f,(_Float16)1.f,(_Float16)1.f,
                      (_Float16)1.f,(_Float16)1.f,(_Float16)1.f,(_Float16)1.f};

    for (int t32 = 0; t32 < 16; ++t32) {
        const int lb = t32 * 32;
        const h8 Aq2 = *(const h8*)&Qh[(lb + lm) * QKS + 8 * hi];
        const f32x16 sc0 = MFMA_32(Aq2, Bk0, shiftacc);  // pre-shifted scores
        const f32x16 sc1 = MFMA_32(Aq2, Bk1, shiftacc);

        float pA[16], pB[16];
        #pragma unroll
        for (int r = 0; r < 16; ++r) pA[r] = __builtin_amdgcn_exp2f(sc0[r]);
        #pragma unroll
        for (int r = 0; r < 16; ++r) pB[r] = __builtin_amdgcn_exp2f(sc1[r]);

        const unsigned int a0 = cvt_pk_u(pA[0],  pA[1]);
        const unsigned int a1 = cvt_pk_u(pA[2],  pA[3]);
        const unsigned int a2 = cvt_pk_u(pA[4],  pA[5]);
        const unsigned int a3 = cvt_pk_u(pA[6],  pA[7]);
        const unsigned int a4 = cvt_pk_u(pA[8],  pA[9]);
        const unsigned int a5 = cvt_pk_u(pA[10], pA[11]);
        const unsigned int a6 = cvt_pk_u(pA[12], pA[13]);
        const unsigned int a7 = cvt_pk_u(pA[14], pA[15]);
        const unsigned int b0 = cvt_pk_u(pB[0],  pB[1]);
        const unsigned int b1 = cvt_pk_u(pB[2],  pB[3]);
        const unsigned int b2 = cvt_pk_u(pB[4],  pB[5]);
        const unsigned int b3 = cvt_pk_u(pB[6],  pB[7]);
        const unsigned int b4 = cvt_pk_u(pB[8],  pB[9]);
        const unsigned int b5 = cvt_pk_u(pB[10], pB[11]);
        const unsigned int b6 = cvt_pk_u(pB[12], pB[13]);
        const unsigned int b7 = cvt_pk_u(pB[14], pB[15]);

        const u32x2 sA02 = __builtin_amdgcn_permlane32_swap(a0, a2, false, false);
        const u32x2 sA13 = __builtin_amdgcn_permlane32_swap(a1, a3, false, false);
        const u32x2 sA46 = __builtin_amdgcn_permlane32_swap(a4, a6, false, false);
        const u32x2 sA57 = __builtin_amdgcn_permlane32_swap(a5, a7, false, false);
        const u32x2 sB02 = __builtin_amdgcn_permlane32_swap(b0, b2, false, false);
        const u32x2 sB13 = __builtin_amdgcn_permlane32_swap(b1, b3, false, false);
        const u32x2 sB46 = __builtin_amdgcn_permlane32_swap(b4, b6, false, false);
        const u32x2 sB57 = __builtin_amdgcn_permlane32_swap(b5, b7, false, false);
        const h8 A1m0 = __builtin_bit_cast(h8, (u32x4){sA02.x, sA13.x, sA02.y, sA13.y});
        const h8 A2m0 = __builtin_bit_cast(h8, (u32x4){sA46.x, sA57.x, sA46.y, sA57.y});
        const h8 A1m1 = __builtin_bit_cast(h8, (u32x4){sB02.x, sB13.x, sB02.y, sB13.y});
        const h8 A2m1 = __builtin_bit_cast(h8, (u32x4){sB46.x, sB57.x, sB46.y, sB57.y});

        // B-frag: cols 0-15 read V, cols 16-31 are constant 1.0 (Z columns)
        const h8 Bv1r = *(const h8*)&Vs[vrow * VST + lb + 8 * hi];
        const h8 Bv2r = *(const h8*)&Vs[vrow * VST + lb + 16 + 8 * hi];
        const h8 Bv1 = vsel ? Bv1r : ones8;
        const h8 Bv2 = vsel ? Bv2r : ones8;

        pv0 = MFMA_32(A1m0, Bv1, pv0);
        pv0 = MFMA_32(A2m0, Bv2, pv0);
        pv1 = MFMA_32(A1m1, Bv1, pv1);
        pv1 = MFMA_32(A2m1, Bv2, pv1);
    }

    // epilogue: Z[mrow] sits in cols 16-31 (lane 16+32hi has col 16).
    const int kk = (NH_ - 1 - n) * 16 + l16;
    const int zlane = 16 + 32 * hi;
    _Float16* Hb = Ht + (size_t)b * 512 * 128;
    #pragma unroll
    for (int r = 0; r < 16; ++r) {
        const int mrow = (r & 3) + 8 * (r >> 2) + 4 * hi;
        const float zr0  = __shfl(pv0[r], zlane);
        const float zr1  = __shfl(pv1[r], zlane);
        const float rz0 = __builtin_amdgcn_rcpf(zr0);
        const float rz1 = __builtin_amdgcn_rcpf(zr1);
        if (lm < 16) {
            Hb[(size_t)(m0 + mrow) * 128 + kk]      = (_Float16)(pv0[r] * rz0);
            Hb[(size_t)(m0 + 32 + mrow) * 128 + kk] = (_Float16)(pv1[r] * rz1);
        }
    }
}

// ---------------------------------------------------------------------------
// Kernel B: out[b] = Wo[b] (128x128) @ heads[b] (128x512), fp16 MFMA,
// pure-register. grid (8 col-tiles, 32 b), 512 thr; wave = 16-row m-tile.
// ---------------------------------------------------------------------------
__global__ __launch_bounds__(512) void out_proj_mfma(
    const float* __restrict__ Wo,        // [B][128][128]
    const _Float16* __restrict__ Ht,     // [B][512][128]
    float* __restrict__ out)             // [B][128][512]
{
    const int ct = blockIdx.x;     // col0 = ct*64
    const int b  = blockIdx.y;
    const int t  = threadIdx.x;
    const int wv = t >> 6;
    const int ln = t & 63;
    const int l16 = ln & 15;
    const int g4  = ln >> 4;

    const float* Wb = Wo + (size_t)b * D_ * D_;
    const _Float16* Hb = Ht + (size_t)b * 512 * 128;

    f32x4 acc[4];
    #pragma unroll
    for (int nt = 0; nt < 4; ++nt) acc[nt] = (f32x4){0.f,0.f,0.f,0.f};

    #pragma unroll
    for (int ks = 0; ks < 4; ++ks) {
        const int k0 = ks * 32 + g4 * 8;
        const float* ap = Wb + (size_t)(wv * 16 + l16) * D_ + k0;
        h8 Ah;
        #pragma unroll
        for (int j = 0; j < 8; ++j) Ah[j] = (_Float16)ap[j];
        #pragma unroll
        for (int nt = 0; nt < 4; ++nt) {
            const h8 Bh = *(const h8*)&Hb[(size_t)(ct * 64 + nt * 16 + l16) * 128 + k0];
            acc[nt] = MFMA_K32(Ah, Bh, acc[nt]);
        }
    }

    float* ob = out + (size_t)b * D_ * L_;
    #pragma unroll
    for (int nt = 0; nt < 4; ++nt) {
        #pragma unroll
        for (int r = 0; r < 4; ++r) {
            ob[(size_t)(wv * 16 + g4 * 4 + r) * L_ + ct * 64 + nt * 16 + l16] = acc[nt][r];
        }
    }
}

extern "C" void kernel_launch(void* const* d_in, const int* in_sizes, int n_in,
                              void* d_out, int out_size, void* d_ws, size_t ws_size,
                              hipStream_t stream)
{
    const float* x  = (const float*)d_in[0];
    const float* Wq = (const float*)d_in[1];
    const float* Wk = (const float*)d_in[2];
    const float* Wv = (const float*)d_in[3];
    const float* Wo = (const float*)d_in[4];
    float* out = (float*)d_out;

    _Float16* Ht = (_Float16*)d_ws;                       // 4 MB
    _Float16* xt = Ht + (size_t)B_ * 512 * 128;           // 4 MB

    xcast<<<dim3(8, B_), dim3(256), 0, stream>>>(x, xt);
    attn_mfma<<<dim3(NH_ * B_), dim3(512), 0, stream>>>(xt, Wq, Wk, Wv, Ht);
    out_proj_mfma<<<dim3(8, B_), dim3(512), 0, stream>>>(Wo, Ht, out);
}